// Round 1
// baseline (1713.869 us; speedup 1.0000x reference)
//
#include <hip/hip_runtime.h>
#include <hip/hip_bf16.h>
#include <cmath>

// Decoder step: B=128, S=128, H=1024, E=512, V=32000
// m = s*B + b  (enc memory order [S,B,2H] -> flat rows of length 2H)
// Workspace layout (floats):
//   hproj  [128*1024]           off 0
//   scores [16384]              off 131072
//   x      [128*2560]           off 147456   ([embeds | a])
//   c1     [128*3584]           off 475136   ([h_new | a | embeds])
//   gx     [128*3072]           off 933888
//   gh     [128*3072]           off 1327104

#define DEVINL __device__ __forceinline__

typedef __attribute__((ext_vector_type(8))) __bf16 bf16x8;
typedef __attribute__((ext_vector_type(4))) float f32x4;

DEVINL unsigned short f2bf(float f) {
    unsigned u = __builtin_bit_cast(unsigned, f);
    unsigned r = (u + 0x7FFFu + ((u >> 16) & 1u)) >> 16;
    return (unsigned short)r;
}

DEVINL float sigmoidf(float x) { return 1.0f / (1.0f + expf(-x)); }

// ---------------- small prep kernels ----------------

__global__ void embed_gather_k(const int* __restrict__ tl,
                               const float* __restrict__ emb,
                               float* __restrict__ xbuf,
                               float* __restrict__ c1) {
    int id = blockIdx.x * blockDim.x + threadIdx.x;
    if (id >= 128 * 512) return;
    int b = id >> 9, e = id & 511;
    float v = emb[(size_t)tl[b] * 512 + e];
    xbuf[b * 2560 + e] = v;          // x[:, 0:512]
    c1[b * 3584 + 3072 + e] = v;     // c1[:, 3072:3584]
}

// hproj[b,n] = b1[n] + dot(dh[b,:], W1[n, 2048:3072])
__global__ void hproj_k(const float* __restrict__ dh,
                        const float* __restrict__ W1,
                        const float* __restrict__ b1,
                        float* __restrict__ hproj) {
    int id = blockIdx.x * blockDim.x + threadIdx.x;
    if (id >= 128 * 1024) return;
    int b = id >> 10, n = id & 1023;
    const float* w = W1 + (size_t)n * 3072 + 2048;
    const float* h = dh + b * 1024;
    float s = b1[n];
    for (int k = 0; k < 1024; k += 4) {
        s += h[k] * w[k] + h[k + 1] * w[k + 1] + h[k + 2] * w[k + 2] + h[k + 3] * w[k + 3];
    }
    hproj[b * 1024 + n] = s;
}

// ---------------- MFMA GEMM: energy + fused tanh/W2 reduction ----------------
// scores[m] += sum_n W2[n] * tanh( (enc @ W1e^T)[m,n] + hproj[b,n] ),  b = m & 127
// grid: (128 m-tiles, 8 n-tiles), block 256
__global__ void __launch_bounds__(256)
gemm_scores_k(const float* __restrict__ A,     // enc flat [16384, 2048]
              const float* __restrict__ W,     // W1 [1024, 3072], use cols [0,2048)
              const float* __restrict__ hproj, // [128,1024]
              const float* __restrict__ W2,    // [1024]
              float* __restrict__ scores) {    // [16384], pre-zeroed
    __shared__ unsigned short As[128 * 64];
    __shared__ unsigned short Bs[128 * 64];
    const int t = threadIdx.x;
    const int m0 = blockIdx.x * 128;
    const int n0 = blockIdx.y * 128;
    const int wid = t >> 6, lane = t & 63;
    const int wm = (wid >> 1) * 64, wn = (wid & 1) * 64;
    const int quad = lane >> 4, l16 = lane & 15;

    f32x4 acc[4][4] = {};

    for (int k0 = 0; k0 < 2048; k0 += 64) {
        for (int i = 0; i < 8; ++i) {
            int idx = t + i * 256;
            int row = idx >> 4;
            int c4 = (idx & 15) << 2;
            float4 va = *(const float4*)(A + (size_t)(m0 + row) * 2048 + k0 + c4);
            unsigned short* da = &As[row * 64 + c4];
            da[0] = f2bf(va.x); da[1] = f2bf(va.y); da[2] = f2bf(va.z); da[3] = f2bf(va.w);
            float4 vb = *(const float4*)(W + (size_t)(n0 + row) * 3072 + k0 + c4);
            unsigned short* db = &Bs[row * 64 + c4];
            db[0] = f2bf(vb.x); db[1] = f2bf(vb.y); db[2] = f2bf(vb.z); db[3] = f2bf(vb.w);
        }
        __syncthreads();
        for (int kk = 0; kk < 64; kk += 32) {
            bf16x8 af[4], bf[4];
            for (int i = 0; i < 4; ++i)
                af[i] = *(const bf16x8*)&As[(wm + i * 16 + l16) * 64 + kk + quad * 8];
            for (int j = 0; j < 4; ++j)
                bf[j] = *(const bf16x8*)&Bs[(wn + j * 16 + l16) * 64 + kk + quad * 8];
            for (int i = 0; i < 4; ++i)
                for (int j = 0; j < 4; ++j)
                    acc[i][j] = __builtin_amdgcn_mfma_f32_16x16x32_bf16(af[i], bf[j], acc[i][j], 0, 0, 0);
        }
        __syncthreads();
    }

    // epilogue: tanh, * W2, reduce over n within wave, atomic into scores
    for (int i = 0; i < 4; ++i) {
        for (int r = 0; r < 4; ++r) {
            int rowg = m0 + wm + i * 16 + quad * 4 + r;
            int b = rowg & 127;
            float partial = 0.0f;
            for (int j = 0; j < 4; ++j) {
                int colg = n0 + wn + j * 16 + l16;
                float v = tanhf(acc[i][j][r] + hproj[b * 1024 + colg]);
                partial += v * W2[colg];
            }
            for (int off = 1; off < 16; off <<= 1)
                partial += __shfl_xor(partial, off, 64);
            if (l16 == 0) atomicAdd(&scores[rowg], partial);
        }
    }
}

// ---------------- softmax + weighted sum over enc ----------------
// one block per b; a[b,:] written into x[:,512:2560] and c1[:,1024:3072]
__global__ void __launch_bounds__(256)
attn_combine_k(const float* __restrict__ scores,
               const float* __restrict__ enc,
               float* __restrict__ xbuf,
               float* __restrict__ c1) {
    const int b = blockIdx.x;
    const int t = threadIdx.x;
    __shared__ float alpha[128];
    __shared__ float red[256];

    float sc = (t < 128) ? scores[t * 128 + b] : -1e30f;
    red[t] = sc;
    __syncthreads();
    for (int s = 128; s > 0; s >>= 1) {
        if (t < s) red[t] = fmaxf(red[t], red[t + s]);
        __syncthreads();
    }
    float mx = red[0];
    __syncthreads();
    float e = (t < 128) ? expf(sc - mx) : 0.0f;
    red[t] = e;
    __syncthreads();
    for (int s = 128; s > 0; s >>= 1) {
        if (t < s) red[t] += red[t + s];
        __syncthreads();
    }
    float denom = red[0];
    if (t < 128) alpha[t] = e / denom;
    __syncthreads();

    float acc[8] = {};
    for (int s = 0; s < 128; ++s) {
        float al = alpha[s];
        const float* erow = enc + ((size_t)(s * 128 + b)) * 2048;
        for (int i = 0; i < 8; ++i)
            acc[i] += al * erow[t + i * 256];
    }
    for (int i = 0; i < 8; ++i) {
        int d = t + i * 256;
        xbuf[b * 2560 + 512 + d] = acc[i];
        c1[b * 3584 + 1024 + d] = acc[i];
    }
}

// ---------------- generic MFMA GEMM, M=128, C = A @ W^T + bias ----------------
// grid.x = N/128, block 256
__global__ void __launch_bounds__(256)
gemm128_k(const float* __restrict__ A, int lda,
          const float* __restrict__ W, int ldw,
          const float* __restrict__ bias,
          float* __restrict__ C, int ldc, int K) {
    __shared__ unsigned short As[128 * 64];
    __shared__ unsigned short Bs[128 * 64];
    const int t = threadIdx.x;
    const int n0 = blockIdx.x * 128;
    const int wid = t >> 6, lane = t & 63;
    const int wm = (wid >> 1) * 64, wn = (wid & 1) * 64;
    const int quad = lane >> 4, l16 = lane & 15;

    f32x4 acc[4][4] = {};

    for (int k0 = 0; k0 < K; k0 += 64) {
        for (int i = 0; i < 8; ++i) {
            int idx = t + i * 256;
            int row = idx >> 4;
            int c4 = (idx & 15) << 2;
            float4 va = *(const float4*)(A + (size_t)row * lda + k0 + c4);
            unsigned short* da = &As[row * 64 + c4];
            da[0] = f2bf(va.x); da[1] = f2bf(va.y); da[2] = f2bf(va.z); da[3] = f2bf(va.w);
            float4 vb = *(const float4*)(W + (size_t)(n0 + row) * ldw + k0 + c4);
            unsigned short* db = &Bs[row * 64 + c4];
            db[0] = f2bf(vb.x); db[1] = f2bf(vb.y); db[2] = f2bf(vb.z); db[3] = f2bf(vb.w);
        }
        __syncthreads();
        for (int kk = 0; kk < 64; kk += 32) {
            bf16x8 af[4], bf[4];
            for (int i = 0; i < 4; ++i)
                af[i] = *(const bf16x8*)&As[(wm + i * 16 + l16) * 64 + kk + quad * 8];
            for (int j = 0; j < 4; ++j)
                bf[j] = *(const bf16x8*)&Bs[(wn + j * 16 + l16) * 64 + kk + quad * 8];
            for (int i = 0; i < 4; ++i)
                for (int j = 0; j < 4; ++j)
                    acc[i][j] = __builtin_amdgcn_mfma_f32_16x16x32_bf16(af[i], bf[j], acc[i][j], 0, 0, 0);
        }
        __syncthreads();
    }

    for (int i = 0; i < 4; ++i) {
        for (int j = 0; j < 4; ++j) {
            int colg = n0 + wn + j * 16 + l16;
            float bv = bias[colg];
            for (int r = 0; r < 4; ++r) {
                int rowg = wm + i * 16 + quad * 4 + r;
                C[(size_t)rowg * ldc + colg] = acc[i][j][r] + bv;
            }
        }
    }
}

// ---------------- GRU gates ----------------
__global__ void gru_gates_k(const float* __restrict__ gx,
                            const float* __restrict__ gh,
                            const float* __restrict__ dh,
                            float* __restrict__ out_h,
                            float* __restrict__ c1) {
    int id = blockIdx.x * blockDim.x + threadIdx.x;
    if (id >= 128 * 1024) return;
    int b = id >> 10, h = id & 1023;
    const float* gxb = gx + b * 3072;
    const float* ghb = gh + b * 3072;
    float r = sigmoidf(gxb[h] + ghb[h]);
    float z = sigmoidf(gxb[1024 + h] + ghb[1024 + h]);
    float n = tanhf(gxb[2048 + h] + r * ghb[2048 + h]);
    float hprev = dh[b * 1024 + h];
    float hnew = (1.0f - z) * n + z * hprev;
    out_h[b * 1024 + h] = hnew;
    c1[b * 3584 + h] = hnew;
}

// ---------------- launch ----------------
extern "C" void kernel_launch(void* const* d_in, const int* in_sizes, int n_in,
                              void* d_out, int out_size, void* d_ws, size_t ws_size,
                              hipStream_t stream) {
    const int* tl = (const int*)d_in[0];
    const float* dh = (const float*)d_in[1];
    const float* enc = (const float*)d_in[2];
    const float* emb = (const float*)d_in[3];
    const float* W1 = (const float*)d_in[4];
    const float* b1 = (const float*)d_in[5];
    const float* W2 = (const float*)d_in[6];
    // d_in[7] = b2: softmax is shift-invariant and scores are not an output -> unused
    const float* Wih = (const float*)d_in[8];
    const float* Whh = (const float*)d_in[9];
    const float* bih = (const float*)d_in[10];
    const float* bhh = (const float*)d_in[11];
    const float* Wout = (const float*)d_in[12];
    const float* bout = (const float*)d_in[13];

    float* out_pred = (float*)d_out;                        // [128, 32000]
    float* out_h = out_pred + (size_t)128 * 32000;          // [128, 1024]

    float* ws = (float*)d_ws;
    float* hproj = ws;                  // 131072
    float* scores = ws + 131072;        // 16384
    float* xbuf = ws + 147456;          // 327680
    float* c1 = ws + 475136;            // 458752
    float* gx = ws + 933888;            // 393216
    float* gh = ws + 1327104;           // 393216

    embed_gather_k<<<(128 * 512 + 255) / 256, 256, 0, stream>>>(tl, emb, xbuf, c1);
    hproj_k<<<(128 * 1024 + 255) / 256, 256, 0, stream>>>(dh, W1, b1, hproj);
    hipMemsetAsync(scores, 0, 16384 * sizeof(float), stream);

    dim3 g1(128, 8);
    gemm_scores_k<<<g1, 256, 0, stream>>>(enc, W1, hproj, W2, scores);

    attn_combine_k<<<128, 256, 0, stream>>>(scores, enc, xbuf, c1);

    gemm128_k<<<24, 256, 0, stream>>>(xbuf, 2560, Wih, 2560, bih, gx, 3072, 2560);
    gemm128_k<<<24, 256, 0, stream>>>(dh, 1024, Whh, 1024, bhh, gh, 3072, 1024);

    gru_gates_k<<<(128 * 1024 + 255) / 256, 256, 0, stream>>>(gx, gh, dh, out_h, c1);

    gemm128_k<<<250, 256, 0, stream>>>(c1, 3584, Wout, 3584, bout, out_pred, 32000, 3584);
}

// Round 2
// 1193.076 us; speedup vs baseline: 1.4365x; 1.4365x over previous
//
#include <hip/hip_runtime.h>
#include <hip/hip_bf16.h>
#include <cmath>

// Decoder step: B=128, S=128, H=1024, E=512, V=32000
// ws layout (float units):
//   hproj f32 [128*1024]      off 0
//   scores f32 [16384]        off 131072
//   xbuf bf16 [128*2560]      off 147456  (163840 floats of space)
//   c1   bf16 [128*3584]      off 311296  (229376 floats of space)
//   gx   f32 [128*3072]       off 540672
//   gh   f32 [128*3072]       off 933888
//   total 1327104 floats = 5.31 MB (< 6.88 MB proven OK in R1)

#define DEVINL __device__ __forceinline__

typedef __attribute__((ext_vector_type(8))) __bf16 bf16x8;
typedef __attribute__((ext_vector_type(4))) float f32x4;

DEVINL unsigned short f2bf(float f) {
    unsigned u = __builtin_bit_cast(unsigned, f);
    unsigned r = (u + 0x7FFFu + ((u >> 16) & 1u)) >> 16;
    return (unsigned short)r;
}

DEVINL float fast_tanh(float x) {
    x = fminf(15.0f, fmaxf(-15.0f, x));
    float e = __expf(2.0f * x);
    return (e - 1.0f) / (e + 1.0f);
}

DEVINL float sigmoidf_(float x) { return 1.0f / (1.0f + __expf(-x)); }

// ---------------- prep ----------------

__global__ void embed_gather_k(const int* __restrict__ tl,
                               const float* __restrict__ emb,
                               unsigned short* __restrict__ xbuf,
                               unsigned short* __restrict__ c1) {
    int id = blockIdx.x * blockDim.x + threadIdx.x;
    if (id >= 128 * 512) return;
    int b = id >> 9, e = id & 511;
    unsigned short v = f2bf(emb[(size_t)tl[b] * 512 + e]);
    xbuf[b * 2560 + e] = v;
    c1[b * 3584 + 3072 + e] = v;
}

// ---------------- unified dbuf MFMA GEMM ----------------
// C[128 x N] = A[128 x K] @ W[N x K]^T (+bias). Tiles: BM=128, BN, BK=64.
// ADT: 0 = A fp32 (converted during staging), 1 = A bf16 (direct copy)
// EPI: 0 = bias add + fp32 store; 1 = fused tanh/W2 score reduction
template<int BN, int ADT, int EPI>
__global__ void __launch_bounds__(256)
gemm_tpl(const void* __restrict__ Av, int lda,
         const float* __restrict__ W, int ldw,
         const float* __restrict__ bias,
         float* __restrict__ C, int ldc, int K,
         const float* __restrict__ hproj,
         const float* __restrict__ W2v,
         float* __restrict__ scores) {
    constexpr int JF = BN / 32;          // n-frags per wave
    constexpr int A_F4 = 8;              // fp32 A: float4 loads / thread
    constexpr int A_U4 = 4;              // bf16 A: 16B loads / thread
    constexpr int W_F4 = BN / 16;        // fp32 W: float4 loads / thread

    __shared__ unsigned short As[2][128 * 64];
    __shared__ unsigned short Bs[2][BN * 64];

    const int t = threadIdx.x;
    const int m0 = (EPI == 1) ? blockIdx.x * 128 : 0;
    const int n0 = (EPI == 1) ? blockIdx.y * BN : blockIdx.x * BN;
    const int wid = t >> 6, lane = t & 63;
    const int wm = (wid & 1) * 64;
    const int wn = (wid >> 1) * (JF * 16);
    const int quad = lane >> 4, l16 = lane & 15;

    const float* Af = (const float*)Av;
    const unsigned short* Ab = (const unsigned short*)Av;

    f32x4 acc[4][JF] = {};
    float4 pa[ADT == 0 ? A_F4 : 1];
    uint4 pab[ADT == 1 ? A_U4 : 1];
    float4 pw[W_F4];

    auto issue = [&](int k0) {
        if constexpr (ADT == 0) {
            for (int i = 0; i < A_F4; ++i) {
                int idx = t + i * 256, row = idx >> 4, c4 = (idx & 15) * 4;
                pa[i] = *(const float4*)(Af + (size_t)(m0 + row) * lda + k0 + c4);
            }
        } else {
            for (int i = 0; i < A_U4; ++i) {
                int idx = t + i * 256, row = idx >> 3, c8 = (idx & 7) * 8;
                pab[i] = *(const uint4*)(Ab + (size_t)(m0 + row) * lda + k0 + c8);
            }
        }
        for (int i = 0; i < W_F4; ++i) {
            int idx = t + i * 256, row = idx >> 4, c4 = (idx & 15) * 4;
            pw[i] = *(const float4*)(W + (size_t)(n0 + row) * ldw + k0 + c4);
        }
    };
    auto commit = [&](int buf) {
        if constexpr (ADT == 0) {
            for (int i = 0; i < A_F4; ++i) {
                int idx = t + i * 256, row = idx >> 4, c4 = (idx & 15) * 4;
                ushort4 s;
                s.x = f2bf(pa[i].x); s.y = f2bf(pa[i].y);
                s.z = f2bf(pa[i].z); s.w = f2bf(pa[i].w);
                *(ushort4*)&As[buf][row * 64 + c4] = s;
            }
        } else {
            for (int i = 0; i < A_U4; ++i) {
                int idx = t + i * 256, row = idx >> 3, c8 = (idx & 7) * 8;
                *(uint4*)&As[buf][row * 64 + c8] = pab[i];
            }
        }
        for (int i = 0; i < W_F4; ++i) {
            int idx = t + i * 256, row = idx >> 4, c4 = (idx & 15) * 4;
            ushort4 s;
            s.x = f2bf(pw[i].x); s.y = f2bf(pw[i].y);
            s.z = f2bf(pw[i].z); s.w = f2bf(pw[i].w);
            *(ushort4*)&Bs[buf][row * 64 + c4] = s;
        }
    };

    issue(0);
    commit(0);
    __syncthreads();

    int buf = 0;
    for (int k0 = 0; k0 < K; k0 += 64) {
        bool nxt = (k0 + 64) < K;
        if (nxt) issue(k0 + 64);
        for (int kk = 0; kk < 64; kk += 32) {
            bf16x8 af[4], bfr[JF];
            for (int i = 0; i < 4; ++i)
                af[i] = *(const bf16x8*)&As[buf][(wm + i * 16 + l16) * 64 + kk + quad * 8];
            for (int j = 0; j < JF; ++j)
                bfr[j] = *(const bf16x8*)&Bs[buf][(wn + j * 16 + l16) * 64 + kk + quad * 8];
            for (int i = 0; i < 4; ++i)
                for (int j = 0; j < JF; ++j)
                    acc[i][j] = __builtin_amdgcn_mfma_f32_16x16x32_bf16(af[i], bfr[j], acc[i][j], 0, 0, 0);
        }
        if (nxt) {
            commit(buf ^ 1);
            __syncthreads();
            buf ^= 1;
        }
    }

    if constexpr (EPI == 0) {
        for (int i = 0; i < 4; ++i)
            for (int j = 0; j < JF; ++j) {
                int colg = n0 + wn + j * 16 + l16;
                float bv = bias[colg];
                for (int r = 0; r < 4; ++r) {
                    int rowg = wm + i * 16 + quad * 4 + r;
                    C[(size_t)rowg * ldc + colg] = acc[i][j][r] + bv;
                }
            }
    } else {
        for (int i = 0; i < 4; ++i)
            for (int r = 0; r < 4; ++r) {
                int rowg = m0 + wm + i * 16 + quad * 4 + r;
                int b = rowg & 127;
                float partial = 0.0f;
                for (int j = 0; j < JF; ++j) {
                    int colg = n0 + wn + j * 16 + l16;
                    float v = fast_tanh(acc[i][j][r] + hproj[b * 1024 + colg]);
                    partial += v * W2v[colg];
                }
                partial += __shfl_xor(partial, 1, 64);
                partial += __shfl_xor(partial, 2, 64);
                partial += __shfl_xor(partial, 4, 64);
                partial += __shfl_xor(partial, 8, 64);
                if (l16 == 0) atomicAdd(&scores[rowg], partial);
            }
    }
}

// ---------------- softmax + weighted sum over enc ----------------
__global__ void __launch_bounds__(256)
attn_combine_k(const float* __restrict__ scores,
               const float* __restrict__ enc,
               unsigned short* __restrict__ xbuf,
               unsigned short* __restrict__ c1) {
    const int b = blockIdx.x;
    const int t = threadIdx.x;
    __shared__ float alpha[128];
    __shared__ float red[256];

    float sc = (t < 128) ? scores[t * 128 + b] : -1e30f;
    red[t] = sc;
    __syncthreads();
    for (int s = 128; s > 0; s >>= 1) {
        if (t < s) red[t] = fmaxf(red[t], red[t + s]);
        __syncthreads();
    }
    float mx = red[0];
    __syncthreads();
    float e = (t < 128) ? __expf(sc - mx) : 0.0f;
    red[t] = e;
    __syncthreads();
    for (int s = 128; s > 0; s >>= 1) {
        if (t < s) red[t] += red[t + s];
        __syncthreads();
    }
    float denom = red[0];
    if (t < 128) alpha[t] = e / denom;
    __syncthreads();

    float acc[8] = {};
    for (int s = 0; s < 128; ++s) {
        float al = alpha[s];
        const float* erow = enc + ((size_t)(s * 128 + b)) * 2048;
        for (int i = 0; i < 8; ++i)
            acc[i] += al * erow[t + i * 256];
    }
    for (int i = 0; i < 8; ++i) {
        int d = t + i * 256;
        unsigned short v = f2bf(acc[i]);
        xbuf[b * 2560 + 512 + d] = v;
        c1[b * 3584 + 1024 + d] = v;
    }
}

// ---------------- GRU gates ----------------
__global__ void gru_gates_k(const float* __restrict__ gx,
                            const float* __restrict__ gh,
                            const float* __restrict__ dh,
                            float* __restrict__ out_h,
                            unsigned short* __restrict__ c1) {
    int id = blockIdx.x * blockDim.x + threadIdx.x;
    if (id >= 128 * 1024) return;
    int b = id >> 10, h = id & 1023;
    const float* gxb = gx + b * 3072;
    const float* ghb = gh + b * 3072;
    float r = sigmoidf_(gxb[h] + ghb[h]);
    float z = sigmoidf_(gxb[1024 + h] + ghb[1024 + h]);
    float n = fast_tanh(gxb[2048 + h] + r * ghb[2048 + h]);
    float hprev = dh[b * 1024 + h];
    float hnew = (1.0f - z) * n + z * hprev;
    out_h[b * 1024 + h] = hnew;
    c1[b * 3584 + h] = f2bf(hnew);
}

// ---------------- launch ----------------
extern "C" void kernel_launch(void* const* d_in, const int* in_sizes, int n_in,
                              void* d_out, int out_size, void* d_ws, size_t ws_size,
                              hipStream_t stream) {
    const int* tl = (const int*)d_in[0];
    const float* dh = (const float*)d_in[1];
    const float* enc = (const float*)d_in[2];
    const float* emb = (const float*)d_in[3];
    const float* W1 = (const float*)d_in[4];
    const float* b1 = (const float*)d_in[5];
    const float* W2 = (const float*)d_in[6];
    // d_in[7] = b2: softmax shift-invariant, scores not an output -> unused
    const float* Wih = (const float*)d_in[8];
    const float* Whh = (const float*)d_in[9];
    const float* bih = (const float*)d_in[10];
    const float* bhh = (const float*)d_in[11];
    const float* Wout = (const float*)d_in[12];
    const float* bout = (const float*)d_in[13];

    float* out_pred = (float*)d_out;                 // [128, 32000]
    float* out_h = out_pred + (size_t)128 * 32000;   // [128, 1024]

    float* ws = (float*)d_ws;
    float* hproj = ws;                                        // 131072 f
    float* scores = ws + 131072;                              // 16384 f
    unsigned short* xbuf = (unsigned short*)(ws + 147456);    // 327680 bf16
    unsigned short* c1 = (unsigned short*)(ws + 311296);      // 458752 bf16
    float* gx = ws + 540672;                                  // 393216 f
    float* gh = ws + 933888;                                  // 393216 f

    embed_gather_k<<<256, 256, 0, stream>>>(tl, emb, xbuf, c1);

    // hproj = dh @ W1[:, 2048:3072]^T + b1   (K=1024, N=1024)
    gemm_tpl<64, 0, 0><<<16, 256, 0, stream>>>(
        dh, 1024, W1 + 2048, 3072, b1, hproj, 1024, 1024, nullptr, nullptr, nullptr);

    // gh = dh @ Whh^T + bhh   (K=1024, N=3072)
    gemm_tpl<64, 0, 0><<<48, 256, 0, stream>>>(
        dh, 1024, Whh, 1024, bhh, gh, 3072, 1024, nullptr, nullptr, nullptr);

    hipMemsetAsync(scores, 0, 16384 * sizeof(float), stream);

    // scores[m] = sum_n W2[n] * tanh( (enc @ W1e^T)[m,n] + hproj[m&127, n] )
    dim3 gs(128, 8);
    gemm_tpl<128, 0, 1><<<gs, 256, 0, stream>>>(
        enc, 2048, W1, 3072, nullptr, nullptr, 0, 2048, hproj, W2, scores);

    attn_combine_k<<<128, 256, 0, stream>>>(scores, enc, xbuf, c1);

    // gx = x @ Wih^T + bih   (A bf16, K=2560, N=3072)
    gemm_tpl<64, 1, 0><<<48, 256, 0, stream>>>(
        xbuf, 2560, Wih, 2560, bih, gx, 3072, 2560, nullptr, nullptr, nullptr);

    gru_gates_k<<<512, 256, 0, stream>>>(gx, gh, dh, out_h, c1);

    // pred = c1 @ Wout^T + bout   (A bf16, K=3584, N=32000)
    gemm_tpl<64, 1, 0><<<500, 256, 0, stream>>>(
        c1, 3584, Wout, 3584, bout, out_pred, 32000, 3584, nullptr, nullptr, nullptr);
}